// Round 1
// baseline (210.853 us; speedup 1.0000x reference)
//
#include <hip/hip_runtime.h>
#include <math.h>

#define BATCH 128
#define LN_EPS 1e-5f

typedef short bf16x8 __attribute__((ext_vector_type(8)));
typedef short bf16x4 __attribute__((ext_vector_type(4)));
typedef float f32x4  __attribute__((ext_vector_type(4)));

__device__ __forceinline__ ushort f2bf(float f) {
    union { float f; unsigned u; } c; c.f = f;
    unsigned r = c.u + 0x7FFF + ((c.u >> 16) & 1);   // round-nearest-even
    return (ushort)(r >> 16);
}

__device__ __forceinline__ float fast_tanh(float v) {
    float e = __expf(2.f * v);
    return 1.f - 2.f / (e + 1.f);
}

// ---------------------------------------------------------------------------
// prep (merged with pe1):
//  - all 128 blocks: one 256-elem slice of Wm23 (bf16 A-frags for cw2/cw3)
//  - block 0: composite token-conv x conv1 -> Wm1 (K=16 A-frag), W0c, W3c
//             (din split 4-ways across the block's 4 waves, LDS-reduced)
//  - all blocks: pe1c tile for (l-block = bx>>2, ch-quarter = bx&3); the
//    cbt boundary biases are recomputed per block from a 4-way din split.
// ---------------------------------------------------------------------------
__global__ __launch_bounds__(256, 2)
void prep_kernel(const float* __restrict__ cw1, const float* __restrict__ cw2,
                 const float* __restrict__ cw3,
                 const float* __restrict__ w3, const float* __restrict__ b3,
                 const float* __restrict__ w5, const float* __restrict__ b5,
                 const float* __restrict__ w7, const float* __restrict__ b7,
                 const float* __restrict__ w9, const float* __restrict__ b9,
                 const float* __restrict__ cb1,
                 ushort* __restrict__ Wm23, ushort* __restrict__ Wm1,
                 float* __restrict__ W0c, float* __restrict__ W3c,
                 float* __restrict__ pe1c) {
    const int tid = threadIdx.x;
    const int bx  = blockIdx.x;
    const int idx = bx * 256 + tid;          // 0 .. 32767 exactly

    __shared__ float tile[64][132];          // PE window (fp32)
    __shared__ float red[4][64][24];         // block-0 composite partials
    __shared__ float cbred[64][4];           // per-block cbt partials

    // ---- Wm23 bf16 A-frags (tap-split layout), 32768 elems over 128 blocks
    {
        int s = idx >> 14, r = idx & 16383;
        int j = r & 7, l15 = (r >> 3) & 15, dt = (r >> 7) & 3;
        int quad = (r >> 9) & 3, k2 = (r >> 11) & 1, kk = (r >> 12) & 3;
        int dout = dt * 16 + l15, din = k2 * 32 + quad * 8 + j;
        const float* cw = (s == 0) ? cw2 : cw3;
        Wm23[idx] = f2bf(cw[dout * 256 + din * 4 + kk]);
    }

    // ---- block 0: composite weights, din-split 4 ways ----
    if (bx == 0) {
        const int ch = tid & 63, part = tid >> 6;
        const float* cw1row = cw1 + ch * 256;
        float acc[24];                        // [0..11]=weff [12..15]=cbt [16..19]=w0c [20..23]=w3c
#pragma unroll
        for (int j = 0; j < 24; ++j) acc[j] = 0.f;
        for (int din = part * 16; din < part * 16 + 16; ++din) {
            int ki = din & 3, g = din >> 2;
            float wl[9];
#pragma unroll
            for (int j = 0; j < 9; ++j) wl[j] = 0.f;
            float bias;
            if (ki == 0)      { for (int j = 0; j < 3; ++j) wl[3 + j] = w3[g * 3 + j]; bias = b3[g]; }
            else if (ki == 1) { for (int j = 0; j < 5; ++j) wl[2 + j] = w5[g * 5 + j]; bias = b5[g]; }
            else if (ki == 2) { for (int j = 0; j < 7; ++j) wl[1 + j] = w7[g * 7 + j]; bias = b7[g]; }
            else              { for (int j = 0; j < 9; ++j) wl[j]     = w9[g * 9 + j]; bias = b9[g]; }
#pragma unroll
            for (int kk = 0; kk < 4; ++kk) {
                float c = cw1row[din * 4 + kk];
                acc[12 + kk] += c * bias;
#pragma unroll
                for (int u = 0; u < 9; ++u) acc[kk + u] += c * wl[u];
            }
            float c0 = cw1row[din * 4 + 0], c3 = cw1row[din * 4 + 3];
#pragma unroll
            for (int u = 0; u < 4; ++u) { acc[16 + u] += c0 * wl[5 + u]; acc[20 + u] += c3 * wl[u]; }
        }
#pragma unroll
        for (int j = 0; j < 24; ++j) red[part][ch][j] = acc[j];
    }

    // ---- per-block cbt partials for this block's 16 channels ----
    {
        const int pair = tid & 63, part = tid >> 6;
        const int kk = pair >> 4, chl = pair & 15;
        const int ch = (bx & 3) * 16 + chl;
        float s = 0.f;
        for (int din = part * 16; din < part * 16 + 16; ++din) {
            int ki = din & 3, g = din >> 2;
            float bias = (ki == 0) ? b3[g] : (ki == 1) ? b5[g] : (ki == 2) ? b7[g] : b9[g];
            s += cw1[ch * 256 + din * 4 + kk] * bias;
        }
        cbred[pair][part] = s;
    }

    // ---- PE window tile: tile[d][pp] = PE(pin0+pp, d) ----
    const int l0 = (bx >> 2) * 64;
    const int pin0 = 2 * l0 - 1;
    for (int i2 = tid; i2 < 64 * 130; i2 += 256) {
        int d = i2 / 130, pp = i2 - d * 130;
        int p = pin0 + pp;
        float v = 0.f;
        if (p >= 0 && p < 4096) {
            float dv = __expf((float)(d & ~1) * -0.14391156831212787f);  // -ln(1e4)/64
            float ang = (float)p * dv;
            v = (d & 1) ? __cosf(ang) : __sinf(ang);
        }
        tile[d][pp] = v;
    }
    __syncthreads();

    // ---- block 0 finalize composite weights ----
    if (bx == 0 && tid < 64) {
        const int ch = tid;
        float w24[24];
#pragma unroll
        for (int j = 0; j < 24; ++j)
            w24[j] = red[0][ch][j] + red[1][ch][j] + red[2][ch][j] + red[3][ch][j];
        int dt = ch >> 4, l15 = ch & 15;
#pragma unroll
        for (int quad = 0; quad < 4; ++quad)
#pragma unroll
            for (int j = 0; j < 8; ++j) {
                int k = quad * 8 + j;
                Wm1[((quad * 4 + dt) * 16 + l15) * 8 + j] = f2bf(k < 12 ? w24[k] : 0.f);
            }
#pragma unroll
        for (int u = 0; u < 4; ++u) { W0c[ch * 4 + u] = w24[16 + u]; W3c[ch * 4 + u] = w24[20 + u]; }
    }

    // ---- pe1c[l][ch] for 64 l x 16 ch: conv1(PE) + bias + valid cbt terms
    const int lane = tid & 63, wv = tid >> 6;
    const int l = l0 + lane;
    const int chl0 = wv * 4;
    const int db = (bx & 3) * 16 + chl0;
    float a4[4];
#pragma unroll
    for (int j = 0; j < 4; ++j) {
        int chl = chl0 + j;
        float cbk0 = cbred[0 * 16 + chl][0] + cbred[0 * 16 + chl][1] + cbred[0 * 16 + chl][2] + cbred[0 * 16 + chl][3];
        float cbk1 = cbred[1 * 16 + chl][0] + cbred[1 * 16 + chl][1] + cbred[1 * 16 + chl][2] + cbred[1 * 16 + chl][3];
        float cbk2 = cbred[2 * 16 + chl][0] + cbred[2 * 16 + chl][1] + cbred[2 * 16 + chl][2] + cbred[2 * 16 + chl][3];
        float cbk3 = cbred[3 * 16 + chl][0] + cbred[3 * 16 + chl][1] + cbred[3 * 16 + chl][2] + cbred[3 * 16 + chl][3];
        float a = cb1[db + j] + cbk1 + cbk2;
        if (l > 0) a += cbk0;
        if (l < 2047) a += cbk3;
        a4[j] = a;
    }
    for (int din = 0; din < 64; ++din) {
        float v0 = tile[din][2 * lane + 0], v1 = tile[din][2 * lane + 1];
        float v2 = tile[din][2 * lane + 2], v3 = tile[din][2 * lane + 3];
        const float* wb = cw1 + din * 4;
#pragma unroll
        for (int j = 0; j < 4; ++j) {
            const float* wj = wb + (db + j) * 256;
            a4[j] = fmaf(v0, wj[0], fmaf(v1, wj[1], fmaf(v2, wj[2], fmaf(v3, wj[3], a4[j]))));
        }
    }
    *(float4*)(pe1c + (size_t)l * 64 + db) = make_float4(a4[0], a4[1], a4[2], a4[3]);
}

// ---------------------------------------------------------------------------
// Fully fused pipeline: block = (batch b, 64 final positions starting g0).
// 512 threads (8 waves): same 63 KB LDS -> still 2 blocks/CU, but 16 waves/CU
// (was 8) and per-wave serial work halves (9 passes over 8 waves instead of 4).
// Stage 3 split across wave pairs by dt so all 8 waves participate.
// ---------------------------------------------------------------------------
__global__ __launch_bounds__(512, 4)
void mega_kernel(const float* __restrict__ x,
                 const ushort* __restrict__ Wm1, const ushort* __restrict__ Wm23,
                 const float* __restrict__ pe1c,
                 const float* __restrict__ W0c, const float* __restrict__ W3c,
                 const float* __restrict__ lg1, const float* __restrict__ lb1,
                 const float* __restrict__ cb2, const float* __restrict__ lg2,
                 const float* __restrict__ lb2, const float* __restrict__ cb3,
                 float* __restrict__ out) {
    const int b = blockIdx.y;
    const int g0 = blockIdx.x * 64;
    const int tid = threadIdx.x;

    __shared__ __align__(16) ushort xs[640];
    __shared__ __align__(16) ushort TE1[148][72];
    __shared__ __align__(16) ushort TO1[148][72];
    __shared__ __align__(16) ushort TE2[66][72];
    __shared__ __align__(16) ushort TO2[66][72];

    // ---- x window -> bf16 LDS: xs[i] = x[8*g0 - 11 + i] ----
    for (int i = tid; i < 640; i += 512) {
        int g = 8 * g0 - 11 + i;
        float v = (g >= 0 && g < 4096) ? x[b * 4096 + g] : 0.f;
        xs[i] = f2bf(v);
    }
    __syncthreads();

    const int wv = tid >> 6, lane = tid & 63;
    const int quad = lane >> 4, l15 = lane & 15;

    // ================= stage 1: h1 positions q = (4g0-3)+m, m<264 ==========
    {
        bf16x8 afr1[4];
#pragma unroll
        for (int dt = 0; dt < 4; ++dt)
            afr1[dt] = *(const bf16x8*)&Wm1[((quad * 4 + dt) * 16 + l15) * 8];
        const int qstart = 4 * g0 - 3;
        for (int pass = wv; pass < 9; pass += 8) {
            const int mb = pass * 32;
            f32x4 a1[2][4];
#pragma unroll
            for (int pt = 0; pt < 2; ++pt) {
                const int m = mb + pt * 16 + l15;
                union { bf16x8 v; unsigned u[4]; } tmp;
                const unsigned* p = (const unsigned*)&xs[2 * m + 8 * quad];
#pragma unroll
                for (int i = 0; i < 4; ++i) tmp.u[i] = p[i];
#pragma unroll
                for (int dt = 0; dt < 4; ++dt)
                    a1[pt][dt] = __builtin_amdgcn_mfma_f32_16x16x32_bf16(
                        afr1[dt], tmp.v, (f32x4)0.f, 0, 0, 0);
            }
#pragma unroll
            for (int pt = 0; pt < 2; ++pt) {
                const int m = mb + pt * 16 + l15;
                if (m >= 264) continue;              // shfl partners share m
                const int q = qstart + m;
                ushort* dst = (m & 1) ? &TE1[(m + 1) >> 1][0] : &TO1[m >> 1][0];
                if (q >= 0 && q < 2048) {
                    float v[16];
                    const float* pb_ = pe1c + (size_t)q * 64;
#pragma unroll
                    for (int dt = 0; dt < 4; ++dt) {
                        float4 pv = *(const float4*)(pb_ + dt * 16 + quad * 4);
                        v[dt * 4 + 0] = a1[pt][dt][0] + pv.x;
                        v[dt * 4 + 1] = a1[pt][dt][1] + pv.y;
                        v[dt * 4 + 2] = a1[pt][dt][2] + pv.z;
                        v[dt * 4 + 3] = a1[pt][dt][3] + pv.w;
                    }
                    if (q == 0 || q == 2047) {       // conv1 pads emb, not x
                        const float* Wc = (q == 0) ? W0c : W3c;
                        const float* xe = x + b * 4096 + ((q == 0) ? 0 : 4092);
                        float x0 = xe[0], x1 = xe[1], x2 = xe[2], x3 = xe[3];
#pragma unroll
                        for (int dt = 0; dt < 4; ++dt)
#pragma unroll
                            for (int r = 0; r < 4; ++r) {
                                const float* wc = Wc + (dt * 16 + quad * 4 + r) * 4;
                                v[dt * 4 + r] -= wc[0] * x0 + wc[1] * x1 + wc[2] * x2 + wc[3] * x3;
                            }
                    }
#pragma unroll
                    for (int i = 0; i < 16; ++i) v[i] = fast_tanh(v[i]);
                    float s = 0.f;
#pragma unroll
                    for (int i = 0; i < 16; ++i) s += v[i];
                    s += __shfl_xor(s, 16, 64);
                    s += __shfl_xor(s, 32, 64);
                    float mean = s * 0.015625f;
                    float qq = 0.f;
#pragma unroll
                    for (int i = 0; i < 16; ++i) { float d = v[i] - mean; qq = fmaf(d, d, qq); }
                    qq += __shfl_xor(qq, 16, 64);
                    qq += __shfl_xor(qq, 32, 64);
                    float rstd = rsqrtf(qq * 0.015625f + LN_EPS);
#pragma unroll
                    for (int dt = 0; dt < 4; ++dt) {
                        bf16x4 pk;
#pragma unroll
                        for (int r = 0; r < 4; ++r) {
                            int ch = dt * 16 + quad * 4 + r;
                            pk[r] = (short)f2bf((v[dt * 4 + r] - mean) * rstd * lg1[ch] + lb1[ch]);
                        }
                        *(bf16x4*)(dst + dt * 16 + quad * 4) = pk;
                    }
                } else {
                    bf16x4 z; z[0] = 0; z[1] = 0; z[2] = 0; z[3] = 0;
#pragma unroll
                    for (int dt = 0; dt < 4; ++dt)
                        *(bf16x4*)(dst + dt * 16 + quad * 4) = z;
                }
            }
        }
    }
    __syncthreads();

    // ================= stage 2: h2 positions p = (2g0-1)+n, n<130 ==========
    for (int pass = wv; pass < 9; pass += 8) {
        const int n = pass * 16 + l15;
        f32x4 a2[4];
#pragma unroll
        for (int dt = 0; dt < 4; ++dt) a2[dt] = (f32x4)0.f;
#pragma unroll
        for (int kk = 0; kk < 4; ++kk) {
            const ushort (*T)[72] = (kk & 1) ? TE1 : TO1;
            const int row = n + ((kk + 1) >> 1);    // kk:0->n 1->n+1 2->n+1 3->n+2
#pragma unroll
            for (int k2 = 0; k2 < 2; ++k2) {
                bf16x8 bfr = *(const bf16x8*)&T[row][k2 * 32 + quad * 8];
                const ushort* wb = Wm23 + ((((kk * 2 + k2) * 4 + quad) * 4) * 16) * 8;
#pragma unroll
                for (int dt = 0; dt < 4; ++dt) {
                    bf16x8 afr = *(const bf16x8*)(wb + ((size_t)(dt * 16 + l15)) * 8);
                    a2[dt] = __builtin_amdgcn_mfma_f32_16x16x32_bf16(afr, bfr, a2[dt], 0, 0, 0);
                }
            }
        }
        if (n < 130) {
            const int p = 2 * g0 - 1 + n;
            ushort* dst = (n & 1) ? &TE2[(n + 1) >> 1][0] : &TO2[n >> 1][0];
            if (p >= 0 && p < 1024) {
                float v[16];
#pragma unroll
                for (int dt = 0; dt < 4; ++dt)
#pragma unroll
                    for (int r = 0; r < 4; ++r)
                        v[dt * 4 + r] = fast_tanh(a2[dt][r] + cb2[dt * 16 + quad * 4 + r]);
                float s = 0.f;
#pragma unroll
                for (int i = 0; i < 16; ++i) s += v[i];
                s += __shfl_xor(s, 16, 64);
                s += __shfl_xor(s, 32, 64);
                float mean = s * 0.015625f;
                float qq = 0.f;
#pragma unroll
                for (int i = 0; i < 16; ++i) { float d = v[i] - mean; qq = fmaf(d, d, qq); }
                qq += __shfl_xor(qq, 16, 64);
                qq += __shfl_xor(qq, 32, 64);
                float rstd = rsqrtf(qq * 0.015625f + LN_EPS);
#pragma unroll
                for (int dt = 0; dt < 4; ++dt) {
                    bf16x4 pk;
#pragma unroll
                    for (int r = 0; r < 4; ++r) {
                        int ch = dt * 16 + quad * 4 + r;
                        pk[r] = (short)f2bf((v[dt * 4 + r] - mean) * rstd * lg2[ch] + lb2[ch]);
                    }
                    *(bf16x4*)(dst + dt * 16 + quad * 4) = pk;
                }
            } else {
                bf16x4 z; z[0] = 0; z[1] = 0; z[2] = 0; z[3] = 0;
#pragma unroll
                for (int dt = 0; dt < 4; ++dt)
                    *(bf16x4*)(dst + dt * 16 + quad * 4) = z;
            }
        }
    }
    __syncthreads();

    // ================= stage 3: final l = g0 + m3, dt split by wave pair ===
    {
        const int m3 = (wv & 3) * 16 + l15;
        const int dth = wv >> 2;                 // waves 0-3: dt{0,1}; 4-7: dt{2,3}
        f32x4 a3[2];
        a3[0] = (f32x4)0.f; a3[1] = (f32x4)0.f;
        const ushort* Wg3 = Wm23 + 16384;
#pragma unroll
        for (int kk = 0; kk < 4; ++kk) {
            const ushort (*T)[72] = (kk & 1) ? TE2 : TO2;
            const int row = m3 + ((kk + 1) >> 1);
#pragma unroll
            for (int k2 = 0; k2 < 2; ++k2) {
                bf16x8 bfr = *(const bf16x8*)&T[row][k2 * 32 + quad * 8];
                const ushort* wb = Wg3 + ((((kk * 2 + k2) * 4 + quad) * 4) * 16) * 8;
#pragma unroll
                for (int d2 = 0; d2 < 2; ++d2) {
                    const int dt = dth * 2 + d2;
                    bf16x8 afr = *(const bf16x8*)(wb + ((size_t)(dt * 16 + l15)) * 8);
                    a3[d2] = __builtin_amdgcn_mfma_f32_16x16x32_bf16(afr, bfr, a3[d2], 0, 0, 0);
                }
            }
        }
        const int l = g0 + m3;
        float* ob = out + ((size_t)(b * 512) + l) * 64;
#pragma unroll
        for (int d2 = 0; d2 < 2; ++d2) {
            const int dt = dth * 2 + d2;
            float4 st = make_float4(fast_tanh(a3[d2][0] + cb3[dt * 16 + quad * 4 + 0]),
                                    fast_tanh(a3[d2][1] + cb3[dt * 16 + quad * 4 + 1]),
                                    fast_tanh(a3[d2][2] + cb3[dt * 16 + quad * 4 + 2]),
                                    fast_tanh(a3[d2][3] + cb3[dt * 16 + quad * 4 + 3]));
            *(float4*)(ob + dt * 16 + quad * 4) = st;
        }
    }
}

extern "C" void kernel_launch(void* const* d_in, const int* in_sizes, int n_in,
                              void* d_out, int out_size, void* d_ws, size_t ws_size,
                              hipStream_t stream) {
    (void)in_sizes; (void)n_in; (void)out_size; (void)ws_size;
    const float* x   = (const float*)d_in[0];
    const float* w3  = (const float*)d_in[1];
    const float* b3  = (const float*)d_in[2];
    const float* w5  = (const float*)d_in[3];
    const float* b5  = (const float*)d_in[4];
    const float* w7  = (const float*)d_in[5];
    const float* b7  = (const float*)d_in[6];
    const float* w9  = (const float*)d_in[7];
    const float* b9  = (const float*)d_in[8];
    const float* cw1 = (const float*)d_in[9];
    const float* cb1 = (const float*)d_in[10];
    const float* cw2 = (const float*)d_in[11];
    const float* cb2 = (const float*)d_in[12];
    const float* cw3 = (const float*)d_in[13];
    const float* cb3 = (const float*)d_in[14];
    const float* lg1 = (const float*)d_in[15];
    const float* lb1 = (const float*)d_in[16];
    const float* lg2 = (const float*)d_in[17];
    const float* lb2 = (const float*)d_in[18];
    float* out = (float*)d_out;

    // ws layout (bytes) — no HBM intermediates beyond weights + pe1c:
    char* w = (char*)d_ws;
    ushort* Wm23 = (ushort*)(w + 0);          //  65536 B (2 x 16384 bf16)
    ushort* Wm1  = (ushort*)(w + 65536);      //   4096 B (2048 bf16)
    float*  W0c  = (float*)(w + 69632);       //   1024 B
    float*  W3c  = (float*)(w + 70656);       //   1024 B
    float*  pe1c = (float*)(w + 71680);       // 524288 B (2048 x 64 fp32)

    prep_kernel<<<128, 256, 0, stream>>>(cw1, cw2, cw3, w3, b3, w5, b5, w7, b7, w9, b9,
                                         cb1, Wm23, Wm1, W0c, W3c, pe1c);
    mega_kernel<<<dim3(8, BATCH), 512, 0, stream>>>(
        x, Wm1, Wm23, pe1c, W0c, W3c, lg1, lb1, cb2, lg2, lb2, cb3, out);
}

// Round 2
// 166.225 us; speedup vs baseline: 1.2685x; 1.2685x over previous
//
#include <hip/hip_runtime.h>
#include <math.h>

#define BATCH 128
#define LN_EPS 1e-5f

typedef short bf16x8 __attribute__((ext_vector_type(8)));
typedef short bf16x4 __attribute__((ext_vector_type(4)));
typedef float f32x4  __attribute__((ext_vector_type(4)));

__device__ __forceinline__ ushort f2bf(float f) {
    union { float f; unsigned u; } c; c.f = f;
    unsigned r = c.u + 0x7FFF + ((c.u >> 16) & 1);   // round-nearest-even
    return (ushort)(r >> 16);
}

__device__ __forceinline__ float fast_tanh(float v) {
    float e = __expf(2.f * v);
    return 1.f - 2.f / (e + 1.f);
}

// ---------------------------------------------------------------------------
// prep (merged with pe1):
//  - all 128 blocks: one 256-elem slice of Wm23 (bf16 A-frags for cw2/cw3)
//  - block 0: composite token-conv x conv1 -> Wm1 (K=16 A-frag), W0c, W3c
//             (din split 4-ways across the block's 4 waves, LDS-reduced)
//  - all blocks: pe1c tile for (l-block = bx>>2, ch-quarter = bx&3); the
//    cbt boundary biases are recomputed per block from a 4-way din split.
// ---------------------------------------------------------------------------
__global__ __launch_bounds__(256, 2)
void prep_kernel(const float* __restrict__ cw1, const float* __restrict__ cw2,
                 const float* __restrict__ cw3,
                 const float* __restrict__ w3, const float* __restrict__ b3,
                 const float* __restrict__ w5, const float* __restrict__ b5,
                 const float* __restrict__ w7, const float* __restrict__ b7,
                 const float* __restrict__ w9, const float* __restrict__ b9,
                 const float* __restrict__ cb1,
                 ushort* __restrict__ Wm23, ushort* __restrict__ Wm1,
                 float* __restrict__ W0c, float* __restrict__ W3c,
                 float* __restrict__ pe1c) {
    const int tid = threadIdx.x;
    const int bx  = blockIdx.x;
    const int idx = bx * 256 + tid;          // 0 .. 32767 exactly

    __shared__ float tile[64][132];          // PE window (fp32)
    __shared__ float red[4][64][24];         // block-0 composite partials
    __shared__ float cbred[64][4];           // per-block cbt partials

    // ---- Wm23 bf16 A-frags (tap-split layout), 32768 elems over 128 blocks
    {
        int s = idx >> 14, r = idx & 16383;
        int j = r & 7, l15 = (r >> 3) & 15, dt = (r >> 7) & 3;
        int quad = (r >> 9) & 3, k2 = (r >> 11) & 1, kk = (r >> 12) & 3;
        int dout = dt * 16 + l15, din = k2 * 32 + quad * 8 + j;
        const float* cw = (s == 0) ? cw2 : cw3;
        Wm23[idx] = f2bf(cw[dout * 256 + din * 4 + kk]);
    }

    // ---- block 0: composite weights, din-split 4 ways ----
    if (bx == 0) {
        const int ch = tid & 63, part = tid >> 6;
        const float* cw1row = cw1 + ch * 256;
        float acc[24];                        // [0..11]=weff [12..15]=cbt [16..19]=w0c [20..23]=w3c
#pragma unroll
        for (int j = 0; j < 24; ++j) acc[j] = 0.f;
        for (int din = part * 16; din < part * 16 + 16; ++din) {
            int ki = din & 3, g = din >> 2;
            float wl[9];
#pragma unroll
            for (int j = 0; j < 9; ++j) wl[j] = 0.f;
            float bias;
            if (ki == 0)      { for (int j = 0; j < 3; ++j) wl[3 + j] = w3[g * 3 + j]; bias = b3[g]; }
            else if (ki == 1) { for (int j = 0; j < 5; ++j) wl[2 + j] = w5[g * 5 + j]; bias = b5[g]; }
            else if (ki == 2) { for (int j = 0; j < 7; ++j) wl[1 + j] = w7[g * 7 + j]; bias = b7[g]; }
            else              { for (int j = 0; j < 9; ++j) wl[j]     = w9[g * 9 + j]; bias = b9[g]; }
#pragma unroll
            for (int kk = 0; kk < 4; ++kk) {
                float c = cw1row[din * 4 + kk];
                acc[12 + kk] += c * bias;
#pragma unroll
                for (int u = 0; u < 9; ++u) acc[kk + u] += c * wl[u];
            }
            float c0 = cw1row[din * 4 + 0], c3 = cw1row[din * 4 + 3];
#pragma unroll
            for (int u = 0; u < 4; ++u) { acc[16 + u] += c0 * wl[5 + u]; acc[20 + u] += c3 * wl[u]; }
        }
#pragma unroll
        for (int j = 0; j < 24; ++j) red[part][ch][j] = acc[j];
    }

    // ---- per-block cbt partials for this block's 16 channels ----
    {
        const int pair = tid & 63, part = tid >> 6;
        const int kk = pair >> 4, chl = pair & 15;
        const int ch = (bx & 3) * 16 + chl;
        float s = 0.f;
        for (int din = part * 16; din < part * 16 + 16; ++din) {
            int ki = din & 3, g = din >> 2;
            float bias = (ki == 0) ? b3[g] : (ki == 1) ? b5[g] : (ki == 2) ? b7[g] : b9[g];
            s += cw1[ch * 256 + din * 4 + kk] * bias;
        }
        cbred[pair][part] = s;
    }

    // ---- PE window tile: tile[d][pp] = PE(pin0+pp, d) ----
    const int l0 = (bx >> 2) * 64;
    const int pin0 = 2 * l0 - 1;
    for (int i2 = tid; i2 < 64 * 130; i2 += 256) {
        int d = i2 / 130, pp = i2 - d * 130;
        int p = pin0 + pp;
        float v = 0.f;
        if (p >= 0 && p < 4096) {
            float dv = __expf((float)(d & ~1) * -0.14391156831212787f);  // -ln(1e4)/64
            float ang = (float)p * dv;
            v = (d & 1) ? __cosf(ang) : __sinf(ang);
        }
        tile[d][pp] = v;
    }
    __syncthreads();

    // ---- block 0 finalize composite weights ----
    if (bx == 0 && tid < 64) {
        const int ch = tid;
        float w24[24];
#pragma unroll
        for (int j = 0; j < 24; ++j)
            w24[j] = red[0][ch][j] + red[1][ch][j] + red[2][ch][j] + red[3][ch][j];
        int dt = ch >> 4, l15 = ch & 15;
#pragma unroll
        for (int quad = 0; quad < 4; ++quad)
#pragma unroll
            for (int j = 0; j < 8; ++j) {
                int k = quad * 8 + j;
                Wm1[((quad * 4 + dt) * 16 + l15) * 8 + j] = f2bf(k < 12 ? w24[k] : 0.f);
            }
#pragma unroll
        for (int u = 0; u < 4; ++u) { W0c[ch * 4 + u] = w24[16 + u]; W3c[ch * 4 + u] = w24[20 + u]; }
    }

    // ---- pe1c[l][ch] for 64 l x 16 ch: conv1(PE) + bias + valid cbt terms
    const int lane = tid & 63, wv = tid >> 6;
    const int l = l0 + lane;
    const int chl0 = wv * 4;
    const int db = (bx & 3) * 16 + chl0;
    float a4[4];
#pragma unroll
    for (int j = 0; j < 4; ++j) {
        int chl = chl0 + j;
        float cbk0 = cbred[0 * 16 + chl][0] + cbred[0 * 16 + chl][1] + cbred[0 * 16 + chl][2] + cbred[0 * 16 + chl][3];
        float cbk1 = cbred[1 * 16 + chl][0] + cbred[1 * 16 + chl][1] + cbred[1 * 16 + chl][2] + cbred[1 * 16 + chl][3];
        float cbk2 = cbred[2 * 16 + chl][0] + cbred[2 * 16 + chl][1] + cbred[2 * 16 + chl][2] + cbred[2 * 16 + chl][3];
        float cbk3 = cbred[3 * 16 + chl][0] + cbred[3 * 16 + chl][1] + cbred[3 * 16 + chl][2] + cbred[3 * 16 + chl][3];
        float a = cb1[db + j] + cbk1 + cbk2;
        if (l > 0) a += cbk0;
        if (l < 2047) a += cbk3;
        a4[j] = a;
    }
    for (int din = 0; din < 64; ++din) {
        float v0 = tile[din][2 * lane + 0], v1 = tile[din][2 * lane + 1];
        float v2 = tile[din][2 * lane + 2], v3 = tile[din][2 * lane + 3];
        const float* wb = cw1 + din * 4;
#pragma unroll
        for (int j = 0; j < 4; ++j) {
            const float* wj = wb + (db + j) * 256;
            a4[j] = fmaf(v0, wj[0], fmaf(v1, wj[1], fmaf(v2, wj[2], fmaf(v3, wj[3], a4[j]))));
        }
    }
    *(float4*)(pe1c + (size_t)l * 64 + db) = make_float4(a4[0], a4[1], a4[2], a4[3]);
}

// ---------------------------------------------------------------------------
// Fully fused pipeline: block = (batch b, 64 final positions starting g0).
// 512 threads (8 waves): same 63 KB LDS -> 2 blocks/CU, 16 waves/CU.
// __launch_bounds__(512, 2): on this toolchain the 2nd arg acts as min
// BLOCKS/CU — 2 blocks = 16 waves/CU = 4 waves/SIMD -> VGPR budget 128.
// (512,4) forced 8 waves/SIMD -> 64 VGPRs -> 265 MB of spill traffic.
// ---------------------------------------------------------------------------
__global__ __launch_bounds__(512, 2)
void mega_kernel(const float* __restrict__ x,
                 const ushort* __restrict__ Wm1, const ushort* __restrict__ Wm23,
                 const float* __restrict__ pe1c,
                 const float* __restrict__ W0c, const float* __restrict__ W3c,
                 const float* __restrict__ lg1, const float* __restrict__ lb1,
                 const float* __restrict__ cb2, const float* __restrict__ lg2,
                 const float* __restrict__ lb2, const float* __restrict__ cb3,
                 float* __restrict__ out) {
    const int b = blockIdx.y;
    const int g0 = blockIdx.x * 64;
    const int tid = threadIdx.x;

    __shared__ __align__(16) ushort xs[640];
    __shared__ __align__(16) ushort TE1[148][72];
    __shared__ __align__(16) ushort TO1[148][72];
    __shared__ __align__(16) ushort TE2[66][72];
    __shared__ __align__(16) ushort TO2[66][72];

    // ---- x window -> bf16 LDS: xs[i] = x[8*g0 - 11 + i] ----
    for (int i = tid; i < 640; i += 512) {
        int g = 8 * g0 - 11 + i;
        float v = (g >= 0 && g < 4096) ? x[b * 4096 + g] : 0.f;
        xs[i] = f2bf(v);
    }
    __syncthreads();

    const int wv = tid >> 6, lane = tid & 63;
    const int quad = lane >> 4, l15 = lane & 15;

    // ================= stage 1: h1 positions q = (4g0-3)+m, m<264 ==========
    {
        bf16x8 afr1[4];
#pragma unroll
        for (int dt = 0; dt < 4; ++dt)
            afr1[dt] = *(const bf16x8*)&Wm1[((quad * 4 + dt) * 16 + l15) * 8];
        const int qstart = 4 * g0 - 3;
        for (int pass = wv; pass < 9; pass += 8) {
            const int mb = pass * 32;
            f32x4 a1[2][4];
#pragma unroll
            for (int pt = 0; pt < 2; ++pt) {
                const int m = mb + pt * 16 + l15;
                union { bf16x8 v; unsigned u[4]; } tmp;
                const unsigned* p = (const unsigned*)&xs[2 * m + 8 * quad];
#pragma unroll
                for (int i = 0; i < 4; ++i) tmp.u[i] = p[i];
#pragma unroll
                for (int dt = 0; dt < 4; ++dt)
                    a1[pt][dt] = __builtin_amdgcn_mfma_f32_16x16x32_bf16(
                        afr1[dt], tmp.v, (f32x4)0.f, 0, 0, 0);
            }
#pragma unroll
            for (int pt = 0; pt < 2; ++pt) {
                const int m = mb + pt * 16 + l15;
                if (m >= 264) continue;              // shfl partners share m
                const int q = qstart + m;
                ushort* dst = (m & 1) ? &TE1[(m + 1) >> 1][0] : &TO1[m >> 1][0];
                if (q >= 0 && q < 2048) {
                    float v[16];
                    const float* pb_ = pe1c + (size_t)q * 64;
#pragma unroll
                    for (int dt = 0; dt < 4; ++dt) {
                        float4 pv = *(const float4*)(pb_ + dt * 16 + quad * 4);
                        v[dt * 4 + 0] = a1[pt][dt][0] + pv.x;
                        v[dt * 4 + 1] = a1[pt][dt][1] + pv.y;
                        v[dt * 4 + 2] = a1[pt][dt][2] + pv.z;
                        v[dt * 4 + 3] = a1[pt][dt][3] + pv.w;
                    }
                    if (q == 0 || q == 2047) {       // conv1 pads emb, not x
                        const float* Wc = (q == 0) ? W0c : W3c;
                        const float* xe = x + b * 4096 + ((q == 0) ? 0 : 4092);
                        float x0 = xe[0], x1 = xe[1], x2 = xe[2], x3 = xe[3];
#pragma unroll
                        for (int dt = 0; dt < 4; ++dt)
#pragma unroll
                            for (int r = 0; r < 4; ++r) {
                                const float* wc = Wc + (dt * 16 + quad * 4 + r) * 4;
                                v[dt * 4 + r] -= wc[0] * x0 + wc[1] * x1 + wc[2] * x2 + wc[3] * x3;
                            }
                    }
#pragma unroll
                    for (int i = 0; i < 16; ++i) v[i] = fast_tanh(v[i]);
                    float s = 0.f;
#pragma unroll
                    for (int i = 0; i < 16; ++i) s += v[i];
                    s += __shfl_xor(s, 16, 64);
                    s += __shfl_xor(s, 32, 64);
                    float mean = s * 0.015625f;
                    float qq = 0.f;
#pragma unroll
                    for (int i = 0; i < 16; ++i) { float d = v[i] - mean; qq = fmaf(d, d, qq); }
                    qq += __shfl_xor(qq, 16, 64);
                    qq += __shfl_xor(qq, 32, 64);
                    float rstd = rsqrtf(qq * 0.015625f + LN_EPS);
#pragma unroll
                    for (int dt = 0; dt < 4; ++dt) {
                        bf16x4 pk;
#pragma unroll
                        for (int r = 0; r < 4; ++r) {
                            int ch = dt * 16 + quad * 4 + r;
                            pk[r] = (short)f2bf((v[dt * 4 + r] - mean) * rstd * lg1[ch] + lb1[ch]);
                        }
                        *(bf16x4*)(dst + dt * 16 + quad * 4) = pk;
                    }
                } else {
                    bf16x4 z; z[0] = 0; z[1] = 0; z[2] = 0; z[3] = 0;
#pragma unroll
                    for (int dt = 0; dt < 4; ++dt)
                        *(bf16x4*)(dst + dt * 16 + quad * 4) = z;
                }
            }
        }
    }
    __syncthreads();

    // ================= stage 2: h2 positions p = (2g0-1)+n, n<130 ==========
    for (int pass = wv; pass < 9; pass += 8) {
        const int n = pass * 16 + l15;
        f32x4 a2[4];
#pragma unroll
        for (int dt = 0; dt < 4; ++dt) a2[dt] = (f32x4)0.f;
#pragma unroll
        for (int kk = 0; kk < 4; ++kk) {
            const ushort (*T)[72] = (kk & 1) ? TE1 : TO1;
            const int row = n + ((kk + 1) >> 1);    // kk:0->n 1->n+1 2->n+1 3->n+2
#pragma unroll
            for (int k2 = 0; k2 < 2; ++k2) {
                bf16x8 bfr = *(const bf16x8*)&T[row][k2 * 32 + quad * 8];
                const ushort* wb = Wm23 + ((((kk * 2 + k2) * 4 + quad) * 4) * 16) * 8;
#pragma unroll
                for (int dt = 0; dt < 4; ++dt) {
                    bf16x8 afr = *(const bf16x8*)(wb + ((size_t)(dt * 16 + l15)) * 8);
                    a2[dt] = __builtin_amdgcn_mfma_f32_16x16x32_bf16(afr, bfr, a2[dt], 0, 0, 0);
                }
            }
        }
        if (n < 130) {
            const int p = 2 * g0 - 1 + n;
            ushort* dst = (n & 1) ? &TE2[(n + 1) >> 1][0] : &TO2[n >> 1][0];
            if (p >= 0 && p < 1024) {
                float v[16];
#pragma unroll
                for (int dt = 0; dt < 4; ++dt)
#pragma unroll
                    for (int r = 0; r < 4; ++r)
                        v[dt * 4 + r] = fast_tanh(a2[dt][r] + cb2[dt * 16 + quad * 4 + r]);
                float s = 0.f;
#pragma unroll
                for (int i = 0; i < 16; ++i) s += v[i];
                s += __shfl_xor(s, 16, 64);
                s += __shfl_xor(s, 32, 64);
                float mean = s * 0.015625f;
                float qq = 0.f;
#pragma unroll
                for (int i = 0; i < 16; ++i) { float d = v[i] - mean; qq = fmaf(d, d, qq); }
                qq += __shfl_xor(qq, 16, 64);
                qq += __shfl_xor(qq, 32, 64);
                float rstd = rsqrtf(qq * 0.015625f + LN_EPS);
#pragma unroll
                for (int dt = 0; dt < 4; ++dt) {
                    bf16x4 pk;
#pragma unroll
                    for (int r = 0; r < 4; ++r) {
                        int ch = dt * 16 + quad * 4 + r;
                        pk[r] = (short)f2bf((v[dt * 4 + r] - mean) * rstd * lg2[ch] + lb2[ch]);
                    }
                    *(bf16x4*)(dst + dt * 16 + quad * 4) = pk;
                }
            } else {
                bf16x4 z; z[0] = 0; z[1] = 0; z[2] = 0; z[3] = 0;
#pragma unroll
                for (int dt = 0; dt < 4; ++dt)
                    *(bf16x4*)(dst + dt * 16 + quad * 4) = z;
            }
        }
    }
    __syncthreads();

    // ================= stage 3: final l = g0 + m3, dt split by wave pair ===
    {
        const int m3 = (wv & 3) * 16 + l15;
        const int dth = wv >> 2;                 // waves 0-3: dt{0,1}; 4-7: dt{2,3}
        f32x4 a3[2];
        a3[0] = (f32x4)0.f; a3[1] = (f32x4)0.f;
        const ushort* Wg3 = Wm23 + 16384;
#pragma unroll
        for (int kk = 0; kk < 4; ++kk) {
            const ushort (*T)[72] = (kk & 1) ? TE2 : TO2;
            const int row = m3 + ((kk + 1) >> 1);
#pragma unroll
            for (int k2 = 0; k2 < 2; ++k2) {
                bf16x8 bfr = *(const bf16x8*)&T[row][k2 * 32 + quad * 8];
                const ushort* wb = Wg3 + ((((kk * 2 + k2) * 4 + quad) * 4) * 16) * 8;
#pragma unroll
                for (int d2 = 0; d2 < 2; ++d2) {
                    const int dt = dth * 2 + d2;
                    bf16x8 afr = *(const bf16x8*)(wb + ((size_t)(dt * 16 + l15)) * 8);
                    a3[d2] = __builtin_amdgcn_mfma_f32_16x16x32_bf16(afr, bfr, a3[d2], 0, 0, 0);
                }
            }
        }
        const int l = g0 + m3;
        float* ob = out + ((size_t)(b * 512) + l) * 64;
#pragma unroll
        for (int d2 = 0; d2 < 2; ++d2) {
            const int dt = dth * 2 + d2;
            float4 st = make_float4(fast_tanh(a3[d2][0] + cb3[dt * 16 + quad * 4 + 0]),
                                    fast_tanh(a3[d2][1] + cb3[dt * 16 + quad * 4 + 1]),
                                    fast_tanh(a3[d2][2] + cb3[dt * 16 + quad * 4 + 2]),
                                    fast_tanh(a3[d2][3] + cb3[dt * 16 + quad * 4 + 3]));
            *(float4*)(ob + dt * 16 + quad * 4) = st;
        }
    }
}

extern "C" void kernel_launch(void* const* d_in, const int* in_sizes, int n_in,
                              void* d_out, int out_size, void* d_ws, size_t ws_size,
                              hipStream_t stream) {
    (void)in_sizes; (void)n_in; (void)out_size; (void)ws_size;
    const float* x   = (const float*)d_in[0];
    const float* w3  = (const float*)d_in[1];
    const float* b3  = (const float*)d_in[2];
    const float* w5  = (const float*)d_in[3];
    const float* b5  = (const float*)d_in[4];
    const float* w7  = (const float*)d_in[5];
    const float* b7  = (const float*)d_in[6];
    const float* w9  = (const float*)d_in[7];
    const float* b9  = (const float*)d_in[8];
    const float* cw1 = (const float*)d_in[9];
    const float* cb1 = (const float*)d_in[10];
    const float* cw2 = (const float*)d_in[11];
    const float* cb2 = (const float*)d_in[12];
    const float* cw3 = (const float*)d_in[13];
    const float* cb3 = (const float*)d_in[14];
    const float* lg1 = (const float*)d_in[15];
    const float* lb1 = (const float*)d_in[16];
    const float* lg2 = (const float*)d_in[17];
    const float* lb2 = (const float*)d_in[18];
    float* out = (float*)d_out;

    // ws layout (bytes) — no HBM intermediates beyond weights + pe1c:
    char* w = (char*)d_ws;
    ushort* Wm23 = (ushort*)(w + 0);          //  65536 B (2 x 16384 bf16)
    ushort* Wm1  = (ushort*)(w + 65536);      //   4096 B (2048 bf16)
    float*  W0c  = (float*)(w + 69632);       //   1024 B
    float*  W3c  = (float*)(w + 70656);       //   1024 B
    float*  pe1c = (float*)(w + 71680);       // 524288 B (2048 x 64 fp32)

    prep_kernel<<<128, 256, 0, stream>>>(cw1, cw2, cw3, w3, b3, w5, b5, w7, b7, w9, b9,
                                         cb1, Wm23, Wm1, W0c, W3c, pe1c);
    mega_kernel<<<dim3(8, BATCH), 512, 0, stream>>>(
        x, Wm1, Wm23, pe1c, W0c, W3c, lg1, lb1, cb2, lg2, lb2, cb3, out);
}